// Round 1
// baseline (313.206 us; speedup 1.0000x reference)
//
#include <hip/hip_runtime.h>
#include <hip/hip_bf16.h>
#include <stdint.h>

#define BM 128
#define BN 128
#define BK 64

typedef __attribute__((ext_vector_type(8))) short bf16x8;
typedef __attribute__((ext_vector_type(4))) float floatx4;

// ---- helpers ------------------------------------------------------------

__device__ __forceinline__ unsigned short f2bf(float f) {
    unsigned int x;
    __builtin_memcpy(&x, &f, 4);
    unsigned int r = (x + 0x7fffu + ((x >> 16) & 1u)) >> 16;  // RNE
    return (unsigned short)r;
}

__device__ __forceinline__ float bf2f_hi(unsigned int u_hi_masked) {
    float f;
    __builtin_memcpy(&f, &u_hi_masked, 4);
    return f;
}

// async global->LDS, 16B per lane.  LDS dest must be wave-uniform base + lane*16.
__device__ __forceinline__ void async_copy16(const void* g, void* l) {
    __builtin_amdgcn_global_load_lds(
        (const __attribute__((address_space(1))) void*)(uintptr_t)g,
        (__attribute__((address_space(3))) void*)(uint32_t)(uintptr_t)l,
        16, 0, 0);
}

// ---- prep: fp32->bf16 convert of x  +  W^T bf16 of Wq/Wk/Wv -------------

__global__ __launch_bounds__(256) void prep(const float* __restrict__ x,
                                            const float* __restrict__ Wq,
                                            const float* __restrict__ Wk,
                                            const float* __restrict__ Wv,
                                            unsigned short* __restrict__ xb,
                                            unsigned short* __restrict__ wT) {
    __shared__ float tile[32][33];
    int bid = blockIdx.x;
    int tid = threadIdx.x;
    if (bid < 8192) {  // cvt: 8192 blocks x 256 threads x float4
        int i = bid * 256 + tid;
        float4 v = ((const float4*)x)[i];
        ushort4 o;
        o.x = f2bf(v.x);
        o.y = f2bf(v.y);
        o.z = f2bf(v.z);
        o.w = f2bf(v.w);
        ((ushort4*)xb)[i] = o;
    } else {  // transpose W: 3 x 1024 blocks, 32x32 tiles
        int w = bid - 8192;
        int z = w >> 10;
        int r = w & 1023;
        int bx = (r & 31) * 32;  // input col (n)
        int by = (r >> 5) * 32;  // input row (k)
        const float* W = z == 0 ? Wq : (z == 1 ? Wk : Wv);
        int tx = tid & 31, ty = tid >> 5;  // 32x8
        for (int rr = 0; rr < 32; rr += 8)
            tile[ty + rr][tx] = W[(size_t)(by + ty + rr) * 1024 + bx + tx];
        __syncthreads();
        unsigned short* o = wT + (size_t)z * 1024 * 1024;
        for (int rr = 0; rr < 32; rr += 8)
            o[(size_t)(bx + ty + rr) * 1024 + by + tx] = f2bf(tile[tx][ty + rr]);
    }
}

// ---- GEMM core: C[m][n] = scale * sum_k A[m][k] * Bt[n][k] --------------
// m97-style: 128x128 tile, BK=64, 4 waves (2x2), 32 16x16x32 bf16 MFMA/wave
// per k-iter, global_load_lds width-16 staging.
//
// R9 (this round):
//  * XOR swizzle (T2, both-sides): LDS dest stays LINEAR (global_load_lds
//    requirement); the per-lane GLOBAL source 16B-chunk is pre-swizzled
//    (ko = ((tid&7)^((tid>>3)&7))*8, q-independent) and fragment reads use
//    kc ^ (fr&7).  Kills the 16-way bank conflict (row stride 128B put all
//    16 fragment lanes on one bank; SQ_LDS_BANK_CONFLICT was 6.7M on pv).
//  * DBUF variant (pv only): 2-phase double-buffer per the T3-minimum
//    recipe — stage(t+1) issued BEFORE compute(t); ONE __syncthreads()
//    (= vmcnt(0)+barrier) per K-step.  pv runs at 2 blocks/CU with
//    complementary pairing, so half the CUs spend most iters with a single
//    live block: the single-buffered stage->drain->compute chain serialized
//    (Occupancy 11.6%, MfmaUtil 12.8%).  Intra-block prefetch hides it.
//    qk/s/vt keep single-buffer (dbuf would halve their 4 blocks/CU).
// Placement model (validated R5/R7): stage time ~= max per-CU BK64-iters
// x 0.805us; blocks land round-robin on CUs (block l -> CU l%256).

template <bool DBUF>
__device__ __forceinline__ void gemm_core_t(const unsigned short* __restrict__ A,
                                            int lda,
                                            const unsigned short* __restrict__ B,
                                            int ldb, void* __restrict__ C,
                                            int ldc, bool out_bf16, int kend,
                                            float scale, int m0, int n0) {
    __shared__ __align__(16) unsigned short As[(DBUF ? 2 : 1) * BM * BK];
    __shared__ __align__(16) unsigned short Bs[(DBUF ? 2 : 1) * BN * BK];

    int tid = threadIdx.x;
    int lane = tid & 63;
    int wave = tid >> 6;
    int wm = (wave >> 1) * 64;
    int wn = (wave & 1) * 64;
    int fr = lane & 15;  // fragment row (m) / col (n)
    int kq = lane >> 4;  // k-quad
    int frs = fr & 7;    // swizzle bits for fragment reads
    // source-side swizzle: chunk slot s=tid&7, row bits r&7=(tid>>3)&7
    int ko = (((tid & 7) ^ ((tid >> 3) & 7)) << 3);

    floatx4 acc[4][4] = {};

    // stage one BK-tile into buffer `buf` (linear LDS dest, swizzled source)
    auto stage = [&](int buf, int k0) {
#pragma unroll
        for (int q = 0; q < 4; q++) {
            int c = tid + q * 256;
            int r = c >> 3;
            async_copy16(A + (size_t)(m0 + r) * lda + k0 + ko,
                         &As[buf * BM * BK + c * 8]);
            async_copy16(B + (size_t)(n0 + r) * ldb + k0 + ko,
                         &Bs[buf * BM * BK + c * 8]);
        }
    };

    auto compute = [&](int buf) {
        const unsigned short* as = &As[buf * BM * BK];
        const unsigned short* bs = &Bs[buf * BM * BK];
#pragma unroll
        for (int kh = 0; kh < 2; kh++) {
            int kcs = ((kh * 4 + kq) ^ frs) * 8;  // swizzled k-chunk offset
            bf16x8 af[4], bfg[4];
#pragma unroll
            for (int mi = 0; mi < 4; mi++)
                af[mi] = *(const bf16x8*)&as[(wm + mi * 16 + fr) * BK + kcs];
#pragma unroll
            for (int ni = 0; ni < 4; ni++)
                bfg[ni] = *(const bf16x8*)&bs[(wn + ni * 16 + fr) * BK + kcs];
#pragma unroll
            for (int mi = 0; mi < 4; mi++)
#pragma unroll
                for (int ni = 0; ni < 4; ni++)
                    acc[mi][ni] = __builtin_amdgcn_mfma_f32_16x16x32_bf16(
                        af[mi], bfg[ni], acc[mi][ni], 0, 0, 0);
        }
    };

    if (DBUF) {
        // 2-phase: stage(t+1) overlaps compute(t); one barrier per K-step.
        // __syncthreads() == s_waitcnt vmcnt(0) lgkmcnt(0) + s_barrier, which
        // is exactly the recipe's "vmcnt(0); barrier" (prefetch had the whole
        // compute phase to land).
        stage(0, 0);
        __syncthreads();
        int nt = kend / BK;
        int cur = 0;
        for (int t = 0; t < nt; t++) {
            if (t + 1 < nt) stage(cur ^ 1, (t + 1) * BK);
            compute(cur);
            __syncthreads();  // drains prefetch + protects buf before rewrite
            cur ^= 1;
        }
    } else {
        for (int k0 = 0; k0 < kend; k0 += BK) {
            stage(0, k0);
            __syncthreads();  // drains vmcnt before LDS reads
            compute(0);
            __syncthreads();  // protect LDS before next stage
        }
    }

    // epilogue: C/D layout col=lane&15, row=(lane>>4)*4+reg  (m89/m91-verified)
    int col0 = n0 + wn + fr;
    int rbase = m0 + wm + kq * 4;
    if (out_bf16) {
        unsigned short* Cb = (unsigned short*)C;
#pragma unroll
        for (int mi = 0; mi < 4; mi++)
#pragma unroll
            for (int ni = 0; ni < 4; ni++)
#pragma unroll
                for (int r = 0; r < 4; r++)
                    Cb[(size_t)(rbase + mi * 16 + r) * ldc + col0 + ni * 16] =
                        f2bf(acc[mi][ni][r] * scale);
    } else {
        float* Cb = (float*)C;
#pragma unroll
        for (int mi = 0; mi < 4; mi++)
#pragma unroll
            for (int ni = 0; ni < 4; ni++)
#pragma unroll
                for (int r = 0; r < 4; r++)
                    Cb[(size_t)(rbase + mi * 16 + r) * ldc + col0 + ni * 16] =
                        acc[mi][ni][r] * scale;
    }
}

// ---- triangular job decode for the S stage ------------------------------

__device__ __forceinline__ void tri_decode(int r2, int& mb, int& nb) {
    mb = (int)((sqrtf(8.0f * r2 + 1.0f) - 1.0f) * 0.5f);
    while ((mb + 1) * (mb + 2) / 2 <= r2) mb++;
    while (mb * (mb + 1) / 2 > r2) mb--;
    nb = r2 - mb * (mb + 1) / 2;
}

// ---- stage B: qk = xb @ [Wq|Wk]  (M=8192, N=2048, K=1024) ---------------
// 1024 blocks = 4/CU x 16 iters = 64 iters/CU, uniform.

__global__ __launch_bounds__(256, 4) void gemm_qk(
    const unsigned short* __restrict__ xb, const unsigned short* __restrict__ wT,
    unsigned short* __restrict__ qk) {
    gemm_core_t<false>(xb, 1024, wT, 1024, qk, 2048, true, 1024, 1.0f,
                       blockIdx.y * BM, blockIdx.x * BN);
}

// ---- stage C: S = scale * Q K^T, lower-triangle blocks only -------------
// 544 blocks; max CU gets 3 blocks = 48 iters.

__global__ __launch_bounds__(256, 4) void gemm_s(
    const unsigned short* __restrict__ qk, unsigned short* __restrict__ S) {
    int bz = blockIdx.x / 136;
    int mb, nb;
    tri_decode(blockIdx.x - bz * 136, mb, nb);
    const unsigned short* Q = qk + (size_t)bz * 2048 * 2048;
    gemm_core_t<false>(Q, 2048, Q + 1024, 2048, S + (size_t)bz * 2048 * 2048,
                       2048, true, 1024, 0.03125f, mb * BM, nb * BN);
}

// ---- stage D: softmax (causal, in place)  MERGED WITH  vt = WvT @ xb^T --
// Softmax: ONE row per wave (2048 blocks x 4 waves = 8192 rows exactly).
// R8 bug: a two-rows-per-wave loop here wrote rows 8192..12287 — 16 MB past
// S, straight into vt. Keep the row map 1:1 with the grid.

__global__ __launch_bounds__(256, 4) void sm_vt(
    unsigned short* __restrict__ S, const unsigned short* __restrict__ wTv,
    const unsigned short* __restrict__ xb, unsigned short* __restrict__ vt) {
    int bid = blockIdx.x;
    if (bid < 512) {  // vt: 8 m-blocks x 64 n-blocks (M=1024 WvT, N=8192 xb)
        gemm_core_t<false>(wTv, 1024, xb, 1024, vt, 8192, true, 1024, 1.0f,
                           (bid >> 6) * BM, (bid & 63) * BN);
        return;
    }
    // softmax: one wave per row, full row in registers (32 f32/lane)
    int lane = threadIdx.x & 63;
    int row = (bid - 512) * 4 + (threadIdx.x >> 6);  // 0..8191
    int i = row & 2047;  // causal row index within batch
    unsigned short* s = S + (size_t)row * 2048;

    uint4 raw[4];
#pragma unroll
    for (int c = 0; c < 4; c++) raw[c] = ((const uint4*)s)[lane + c * 64];

    const float NEG = -1.0e30f;
    float p[32];
    float m = NEG;
#pragma unroll
    for (int c = 0; c < 4; c++) {
        const unsigned int* u = (const unsigned int*)&raw[c];
#pragma unroll
        for (int w = 0; w < 4; w++) {
            int j = c * 512 + lane * 8 + w * 2;
            float f0 = bf2f_hi(u[w] << 16);
            float f1 = bf2f_hi(u[w] & 0xffff0000u);
            f0 = (j <= i) ? f0 : NEG;
            f1 = (j + 1 <= i) ? f1 : NEG;
            p[c * 8 + w * 2] = f0;
            p[c * 8 + w * 2 + 1] = f1;
            m = fmaxf(m, fmaxf(f0, f1));
        }
    }
#pragma unroll
    for (int o = 32; o > 0; o >>= 1) m = fmaxf(m, __shfl_xor(m, o));

    float sum = 0.f;
#pragma unroll
    for (int t = 0; t < 32; t++) {
        p[t] = __expf(p[t] - m);
        sum += p[t];
    }
#pragma unroll
    for (int o = 32; o > 0; o >>= 1) sum += __shfl_xor(sum, o);
    float inv = 1.0f / sum;

#pragma unroll
    for (int c = 0; c < 4; c++) {
        uint4 out;
        unsigned int* u = (unsigned int*)&out;
#pragma unroll
        for (int w = 0; w < 4; w++) {
            unsigned int lo = f2bf(p[c * 8 + w * 2] * inv);
            unsigned int hi = f2bf(p[c * 8 + w * 2 + 1] * inv);
            u[w] = lo | (hi << 16);
        }
        ((uint4*)s)[lane + c * 64] = out;
    }
}

// ---- stage E: O = P @ V, complementary kend pairing ---------------------
// Round-robin block->CU: CU c gets blocks c and c+256. Map b<256 -> j=b
// (mb=j>>5 in 0..7), b>=256 -> j=767-b (mb in 8..15): per-CU iters
// = 2(mb+1) + 2(16-mb) = 34, uniform (vs 64 worst-case with same-mb pairing
// — that mispairing alone made PV 51.7us in R5).
// R9: DBUF core — the complementary pair has overlap window only
// 2*min(iters): CU 0 runs 30 of 34 iters with ONE live block. The dbuf
// prefetch makes the solo stretches latency-tolerant.

__global__ __launch_bounds__(256, 4) void gemm_pv(
    const unsigned short* __restrict__ S, const unsigned short* __restrict__ vt,
    float* __restrict__ out) {
    int b = blockIdx.x;
    int j = b < 256 ? b : 767 - b;
    int mb = j >> 5;
    int rem = j & 31;
    int bz = rem >> 3, nb = rem & 7;
    int kend = (mb + 1) * 128;  // P[i][j]==0 for j>i
    gemm_core_t<true>(S + (size_t)bz * 2048 * 2048, 2048,
                      vt + (size_t)bz * 2048, 8192,
                      out + (size_t)bz * 2048 * 1024, 1024, false, kend, 1.0f,
                      mb * BM, nb * BN);
}

// ---- launch -------------------------------------------------------------

extern "C" void kernel_launch(void* const* d_in, const int* in_sizes, int n_in,
                              void* d_out, int out_size, void* d_ws,
                              size_t ws_size, hipStream_t stream) {
    const float* x = (const float*)d_in[0];
    const float* Wq = (const float*)d_in[1];
    const float* Wk = (const float*)d_in[2];
    const float* Wv = (const float*)d_in[3];
    // causal_mask (d_in[4]) is always 1 in this problem — hardcoded causal.

    char* ws = (char*)d_ws;
    // layout (bytes):
    //   qk [8192][2048] bf16  : 0        .. 33554432   (Q cols 0..1023, K cols 1024..2047)
    //   S  [4][2048][2048]    : 33554432 .. 67108864
    //   vt [1024][8192] bf16  : 67108864 .. 83886080   (V^T, batches side-by-side cols)
    //   xb [8192][1024] bf16  : 83886080 .. 100663296
    //   wT [3][1024][1024]    : 100663296.. 106954752
    unsigned short* qk = (unsigned short*)(ws);
    unsigned short* S = (unsigned short*)(ws + 33554432);
    unsigned short* vt = (unsigned short*)(ws + 67108864);
    unsigned short* xb = (unsigned short*)(ws + 83886080);
    unsigned short* wT = (unsigned short*)(ws + 100663296);

    // A. x->bf16 (8192 blocks) + W->W^T bf16 (3072 blocks), one dispatch
    prep<<<11264, 256, 0, stream>>>(x, Wq, Wk, Wv, xb, wT);
    // B. qk = xb @ [Wq|Wk]   (M=8192, N=2048, K=1024) — 1024 blocks
    gemm_qk<<<dim3(16, 64), 256, 0, stream>>>(xb, wT, qk);
    // C. S = scale * Q K^T — 544 lower-triangle blocks only
    gemm_s<<<544, 256, 0, stream>>>(qk, S);
    // D. softmax (2048 light blocks) + vt GEMM (512 blocks), one dispatch
    sm_vt<<<2560, 256, 0, stream>>>(S, wT + 2 * 1024 * 1024, xb, vt);
    // E. O = P @ V — 512 blocks, complementary kend pairing
    gemm_pv<<<512, 256, 0, stream>>>(S, vt, (float*)d_out);
}

// Round 3
// 239.439 us; speedup vs baseline: 1.3081x; 1.3081x over previous
//
#include <hip/hip_runtime.h>
#include <hip/hip_bf16.h>
#include <stdint.h>

#define BM 128
#define BN 128
#define BK 64

typedef __attribute__((ext_vector_type(8))) short bf16x8;
typedef __attribute__((ext_vector_type(4))) float floatx4;

// ---- helpers ------------------------------------------------------------

__device__ __forceinline__ unsigned short f2bf(float f) {
    unsigned int x;
    __builtin_memcpy(&x, &f, 4);
    unsigned int r = (x + 0x7fffu + ((x >> 16) & 1u)) >> 16;  // RNE
    return (unsigned short)r;
}

__device__ __forceinline__ float bf2f_hi(unsigned int u_hi_masked) {
    float f;
    __builtin_memcpy(&f, &u_hi_masked, 4);
    return f;
}

// async global->LDS, 16B per lane.  LDS dest must be wave-uniform base + lane*16.
// R1 LESSON: the per-lane GLOBAL source order must stay ASCENDING — an XOR
// permutation within the 128B row segment de-coalesced the DMA into 16B
// requests and cost +60% on every staging-bound core (qk 50->80us).
__device__ __forceinline__ void async_copy16(const void* g, void* l) {
    __builtin_amdgcn_global_load_lds(
        (const __attribute__((address_space(1))) void*)(uintptr_t)g,
        (__attribute__((address_space(3))) void*)(uint32_t)(uintptr_t)l,
        16, 0, 0);
}

// ---- prep: fp32->bf16 convert of x  +  W^T bf16 of Wq/Wk/Wv -------------

__global__ __launch_bounds__(256) void prep(const float* __restrict__ x,
                                            const float* __restrict__ Wq,
                                            const float* __restrict__ Wk,
                                            const float* __restrict__ Wv,
                                            unsigned short* __restrict__ xb,
                                            unsigned short* __restrict__ wT) {
    __shared__ float tile[32][33];
    int bid = blockIdx.x;
    int tid = threadIdx.x;
    if (bid < 8192) {  // cvt: 8192 blocks x 256 threads x float4
        int i = bid * 256 + tid;
        float4 v = ((const float4*)x)[i];
        ushort4 o;
        o.x = f2bf(v.x);
        o.y = f2bf(v.y);
        o.z = f2bf(v.z);
        o.w = f2bf(v.w);
        ((ushort4*)xb)[i] = o;
    } else {  // transpose W: 3 x 1024 blocks, 32x32 tiles
        int w = bid - 8192;
        int z = w >> 10;
        int r = w & 1023;
        int bx = (r & 31) * 32;  // input col (n)
        int by = (r >> 5) * 32;  // input row (k)
        const float* W = z == 0 ? Wq : (z == 1 ? Wk : Wv);
        int tx = tid & 31, ty = tid >> 5;  // 32x8
        for (int rr = 0; rr < 32; rr += 8)
            tile[ty + rr][tx] = W[(size_t)(by + ty + rr) * 1024 + bx + tx];
        __syncthreads();
        unsigned short* o = wT + (size_t)z * 1024 * 1024;
        for (int rr = 0; rr < 32; rr += 8)
            o[(size_t)(bx + ty + rr) * 1024 + by + tx] = f2bf(tile[tx][ty + rr]);
    }
}

// ---- GEMM core (single-buffer) — byte-identical to the 249.7us baseline --
// m97-style: 128x128 tile, BK=64, 4 waves (2x2), 32 16x16x32 bf16 MFMA/wave
// per k-iter, global_load_lds width-16 staging into unpadded row-major LDS
// [row][64] (layout = lane order, a hard requirement).
// Placement model (validated R5/R7): stage time ~= max per-CU BK64-iters
// x 0.805us; blocks land round-robin on CUs (block l -> CU l%256).

__device__ __forceinline__ void gemm_core(const unsigned short* __restrict__ A,
                                          int lda,
                                          const unsigned short* __restrict__ B,
                                          int ldb, void* __restrict__ C,
                                          int ldc, bool out_bf16, int kend,
                                          float scale, int m0, int n0) {
    __shared__ __align__(16) unsigned short As[BM * BK];  // 16 KB
    __shared__ __align__(16) unsigned short Bs[BN * BK];  // 16 KB

    int tid = threadIdx.x;
    int lane = tid & 63;
    int wave = tid >> 6;
    int wm = (wave >> 1) * 64;
    int wn = (wave & 1) * 64;
    int fr = lane & 15;  // fragment row (m) / col (n)
    int kq = lane >> 4;  // k-quad

    floatx4 acc[4][4] = {};

    for (int k0 = 0; k0 < kend; k0 += BK) {
#pragma unroll
        for (int q = 0; q < 4; q++) {
            int c = tid + q * 256;
            int r = c >> 3, ko = (c & 7) * 8;
            async_copy16(A + (size_t)(m0 + r) * lda + k0 + ko, &As[c * 8]);
            async_copy16(B + (size_t)(n0 + r) * ldb + k0 + ko, &Bs[c * 8]);
        }
        __syncthreads();  // drains vmcnt before LDS reads

#pragma unroll
        for (int kh = 0; kh < 2; kh++) {
            int kc = kh * 4 + kq;
            bf16x8 af[4], bfg[4];
#pragma unroll
            for (int mi = 0; mi < 4; mi++)
                af[mi] = *(const bf16x8*)&As[(wm + mi * 16 + fr) * BK + kc * 8];
#pragma unroll
            for (int ni = 0; ni < 4; ni++)
                bfg[ni] = *(const bf16x8*)&Bs[(wn + ni * 16 + fr) * BK + kc * 8];
#pragma unroll
            for (int mi = 0; mi < 4; mi++)
#pragma unroll
                for (int ni = 0; ni < 4; ni++)
                    acc[mi][ni] = __builtin_amdgcn_mfma_f32_16x16x32_bf16(
                        af[mi], bfg[ni], acc[mi][ni], 0, 0, 0);
        }
        __syncthreads();  // protect LDS before next stage
    }

    // epilogue: C/D layout col=lane&15, row=(lane>>4)*4+reg  (m89/m91-verified)
    int col0 = n0 + wn + fr;
    int rbase = m0 + wm + kq * 4;
    if (out_bf16) {
        unsigned short* Cb = (unsigned short*)C;
#pragma unroll
        for (int mi = 0; mi < 4; mi++)
#pragma unroll
            for (int ni = 0; ni < 4; ni++)
#pragma unroll
                for (int r = 0; r < 4; r++)
                    Cb[(size_t)(rbase + mi * 16 + r) * ldc + col0 + ni * 16] =
                        f2bf(acc[mi][ni][r] * scale);
    } else {
        float* Cb = (float*)C;
#pragma unroll
        for (int mi = 0; mi < 4; mi++)
#pragma unroll
            for (int ni = 0; ni < 4; ni++)
#pragma unroll
                for (int r = 0; r < 4; r++)
                    Cb[(size_t)(rbase + mi * 16 + r) * ldc + col0 + ni * 16] =
                        acc[mi][ni][r] * scale;
    }
}

// ---- GEMM core (double-buffered, pv only) -------------------------------
// R3: dbuf (T3-minimum) + PADDED-STRIDE segment layout (fixes R2's overlap).
//  * Each wave-issue DMAs one contiguous 1KB segment s (=4q+wave, rows
//    8s..8s+7).  Segment STRIDE is 544 shorts (512 data + 32 pad = 1088B
//    = 272 dwords == 16 banks mod 32).  Segments never overlap (R2 bug:
//    a (s&1)*32 shift without reserved space collided odd seg s with
//    even seg s+1 -> absmax 3.7).  Global per-lane order is byte-identical
//    to the single-buffer core (ascending 128B runs — R1 lesson).
//  * Bank math: a fragment ds_read_b128 (16 lanes, fixed kc) spans 2
//    segments; parity shift 16 banks + kq shift 4kq covers all 8 4-bank
//    groups with 8 lanes each = 8 LDS clk = conflict-free b128 rate
//    (linear layout: 16 lanes on one group = 16 clk, 2x).
//  * dbuf: stage(t+1) issued BEFORE compute(t), ONE __syncthreads()
//    (= vmcnt(0)+barrier) per K-step. pv runs 2 blocks/CU with
//    complementary pairing -> most iters have ONE live block; intra-block
//    prefetch is the only latency hiding available there.
// LDS: 4 x 17408B = 69632B; 2 blocks/CU (139KB < 160KB).

#define SEG_STRIDE 544  // shorts: 512 data + 32 pad (16-bank parity shift)
#define BUF_SH (16 * SEG_STRIDE)  // 8704 shorts = 17408 B

__device__ __forceinline__ void gemm_core_db(
    const unsigned short* __restrict__ A, int lda,
    const unsigned short* __restrict__ B, int ldb, void* __restrict__ C,
    int ldc, bool out_bf16, int kend, float scale, int m0, int n0) {
    __shared__ __align__(16) unsigned short As[2 * BUF_SH];
    __shared__ __align__(16) unsigned short Bs[2 * BUF_SH];

    int tid = threadIdx.x;
    int lane = tid & 63;
    int wave = tid >> 6;
    int wm = (wave >> 1) * 64;
    int wn = (wave & 1) * 64;
    int fr = lane & 15;  // fragment row (m) / col (n)
    int kq = lane >> 4;  // k-quad

    floatx4 acc[4][4] = {};

    auto stage = [&](int buf, int k0) {
#pragma unroll
        for (int q = 0; q < 4; q++) {
            int s = 4 * q + wave;         // 1KB segment, wave-uniform
            int r = s * 8 + (lane >> 3);  // global row (same rows as sbuf core)
            int ko = (lane & 7) * 8;      // ascending chunk order!
            int dst = buf * BUF_SH + s * SEG_STRIDE + lane * 8;
            async_copy16(A + (size_t)(m0 + r) * lda + k0 + ko, &As[dst]);
            async_copy16(B + (size_t)(n0 + r) * ldb + k0 + ko, &Bs[dst]);
        }
    };

    auto compute = [&](int buf) {
        const unsigned short* as = &As[buf * BUF_SH];
        const unsigned short* bs = &Bs[buf * BUF_SH];
#pragma unroll
        for (int kh = 0; kh < 2; kh++) {
            int kc = kh * 4 + kq;
            bf16x8 af[4], bfg[4];
#pragma unroll
            for (int mi = 0; mi < 4; mi++) {
                int row = wm + mi * 16 + fr;
                af[mi] = *(const bf16x8*)&as[(row >> 3) * SEG_STRIDE +
                                             (row & 7) * 64 + kc * 8];
            }
#pragma unroll
            for (int ni = 0; ni < 4; ni++) {
                int row = wn + ni * 16 + fr;
                bfg[ni] = *(const bf16x8*)&bs[(row >> 3) * SEG_STRIDE +
                                              (row & 7) * 64 + kc * 8];
            }
#pragma unroll
            for (int mi = 0; mi < 4; mi++)
#pragma unroll
                for (int ni = 0; ni < 4; ni++)
                    acc[mi][ni] = __builtin_amdgcn_mfma_f32_16x16x32_bf16(
                        af[mi], bfg[ni], acc[mi][ni], 0, 0, 0);
        }
    };

    // 2-phase: stage(t+1) overlaps compute(t); one barrier per K-step.
    stage(0, 0);
    __syncthreads();
    int nt = kend / BK;
    int cur = 0;
    for (int t = 0; t < nt; t++) {
        if (t + 1 < nt) stage(cur ^ 1, (t + 1) * BK);
        compute(cur);
        __syncthreads();  // drains prefetch + protects buf before rewrite
        cur ^= 1;
    }

    // epilogue: C/D layout col=lane&15, row=(lane>>4)*4+reg
    int col0 = n0 + wn + fr;
    int rbase = m0 + wm + kq * 4;
    if (out_bf16) {
        unsigned short* Cb = (unsigned short*)C;
#pragma unroll
        for (int mi = 0; mi < 4; mi++)
#pragma unroll
            for (int ni = 0; ni < 4; ni++)
#pragma unroll
                for (int r = 0; r < 4; r++)
                    Cb[(size_t)(rbase + mi * 16 + r) * ldc + col0 + ni * 16] =
                        f2bf(acc[mi][ni][r] * scale);
    } else {
        float* Cb = (float*)C;
#pragma unroll
        for (int mi = 0; mi < 4; mi++)
#pragma unroll
            for (int ni = 0; ni < 4; ni++)
#pragma unroll
                for (int r = 0; r < 4; r++)
                    Cb[(size_t)(rbase + mi * 16 + r) * ldc + col0 + ni * 16] =
                        acc[mi][ni][r] * scale;
    }
}

// ---- triangular job decode for the S stage ------------------------------

__device__ __forceinline__ void tri_decode(int r2, int& mb, int& nb) {
    mb = (int)((sqrtf(8.0f * r2 + 1.0f) - 1.0f) * 0.5f);
    while ((mb + 1) * (mb + 2) / 2 <= r2) mb++;
    while (mb * (mb + 1) / 2 > r2) mb--;
    nb = r2 - mb * (mb + 1) / 2;
}

// ---- stage B: qk = xb @ [Wq|Wk]  (M=8192, N=2048, K=1024) ---------------
// 1024 blocks = 4/CU x 16 iters = 64 iters/CU, uniform.

__global__ __launch_bounds__(256, 4) void gemm_qk(
    const unsigned short* __restrict__ xb, const unsigned short* __restrict__ wT,
    unsigned short* __restrict__ qk) {
    gemm_core(xb, 1024, wT, 1024, qk, 2048, true, 1024, 1.0f,
              blockIdx.y * BM, blockIdx.x * BN);
}

// ---- stage C: S = scale * Q K^T, lower-triangle blocks only -------------
// 544 blocks; max CU gets 3 blocks = 48 iters.

__global__ __launch_bounds__(256, 4) void gemm_s(
    const unsigned short* __restrict__ qk, unsigned short* __restrict__ S) {
    int bz = blockIdx.x / 136;
    int mb, nb;
    tri_decode(blockIdx.x - bz * 136, mb, nb);
    const unsigned short* Q = qk + (size_t)bz * 2048 * 2048;
    gemm_core(Q, 2048, Q + 1024, 2048, S + (size_t)bz * 2048 * 2048, 2048,
              true, 1024, 0.03125f, mb * BM, nb * BN);
}

// ---- stage D: softmax (causal, in place)  MERGED WITH  vt = WvT @ xb^T --
// Softmax: ONE row per wave (2048 blocks x 4 waves = 8192 rows exactly).
// R8 bug: a two-rows-per-wave loop here wrote rows 8192..12287 — 16 MB past
// S, straight into vt. Keep the row map 1:1 with the grid.

__global__ __launch_bounds__(256, 4) void sm_vt(
    unsigned short* __restrict__ S, const unsigned short* __restrict__ wTv,
    const unsigned short* __restrict__ xb, unsigned short* __restrict__ vt) {
    int bid = blockIdx.x;
    if (bid < 512) {  // vt: 8 m-blocks x 64 n-blocks (M=1024 WvT, N=8192 xb)
        gemm_core(wTv, 1024, xb, 1024, vt, 8192, true, 1024, 1.0f,
                  (bid >> 6) * BM, (bid & 63) * BN);
        return;
    }
    // softmax: one wave per row, full row in registers (32 f32/lane)
    int lane = threadIdx.x & 63;
    int row = (bid - 512) * 4 + (threadIdx.x >> 6);  // 0..8191
    int i = row & 2047;  // causal row index within batch
    unsigned short* s = S + (size_t)row * 2048;

    uint4 raw[4];
#pragma unroll
    for (int c = 0; c < 4; c++) raw[c] = ((const uint4*)s)[lane + c * 64];

    const float NEG = -1.0e30f;
    float p[32];
    float m = NEG;
#pragma unroll
    for (int c = 0; c < 4; c++) {
        const unsigned int* u = (const unsigned int*)&raw[c];
#pragma unroll
        for (int w = 0; w < 4; w++) {
            int j = c * 512 + lane * 8 + w * 2;
            float f0 = bf2f_hi(u[w] << 16);
            float f1 = bf2f_hi(u[w] & 0xffff0000u);
            f0 = (j <= i) ? f0 : NEG;
            f1 = (j + 1 <= i) ? f1 : NEG;
            p[c * 8 + w * 2] = f0;
            p[c * 8 + w * 2 + 1] = f1;
            m = fmaxf(m, fmaxf(f0, f1));
        }
    }
#pragma unroll
    for (int o = 32; o > 0; o >>= 1) m = fmaxf(m, __shfl_xor(m, o));

    float sum = 0.f;
#pragma unroll
    for (int t = 0; t < 32; t++) {
        p[t] = __expf(p[t] - m);
        sum += p[t];
    }
#pragma unroll
    for (int o = 32; o > 0; o >>= 1) sum += __shfl_xor(sum, o);
    float inv = 1.0f / sum;

#pragma unroll
    for (int c = 0; c < 4; c++) {
        uint4 out;
        unsigned int* u = (unsigned int*)&out;
#pragma unroll
        for (int w = 0; w < 4; w++) {
            unsigned int lo = f2bf(p[c * 8 + w * 2] * inv);
            unsigned int hi = f2bf(p[c * 8 + w * 2 + 1] * inv);
            u[w] = lo | (hi << 16);
        }
        ((uint4*)s)[lane + c * 64] = out;
    }
}

// ---- stage E: O = P @ V, complementary kend pairing ---------------------
// Round-robin block->CU: CU c gets blocks c and c+256. Map b<256 -> j=b
// (mb=j>>5 in 0..7), b>=256 -> j=767-b (mb in 8..15): per-CU iters
// = 2(mb+1) + 2(16-mb) = 34, uniform (vs 64 worst-case with same-mb pairing
// — that mispairing alone made PV 51.7us in R5).
// R3: dbuf core + padded-stride segment layout (see gemm_core_db header).

__global__ __launch_bounds__(256, 4) void gemm_pv(
    const unsigned short* __restrict__ S, const unsigned short* __restrict__ vt,
    float* __restrict__ out) {
    int b = blockIdx.x;
    int j = b < 256 ? b : 767 - b;
    int mb = j >> 5;
    int rem = j & 31;
    int bz = rem >> 3, nb = rem & 7;
    int kend = (mb + 1) * 128;  // P[i][j]==0 for j>i
    gemm_core_db(S + (size_t)bz * 2048 * 2048, 2048, vt + (size_t)bz * 2048,
                 8192, out + (size_t)bz * 2048 * 1024, 1024, false, kend, 1.0f,
                 mb * BM, nb * BN);
}

// ---- launch -------------------------------------------------------------

extern "C" void kernel_launch(void* const* d_in, const int* in_sizes, int n_in,
                              void* d_out, int out_size, void* d_ws,
                              size_t ws_size, hipStream_t stream) {
    const float* x = (const float*)d_in[0];
    const float* Wq = (const float*)d_in[1];
    const float* Wk = (const float*)d_in[2];
    const float* Wv = (const float*)d_in[3];
    // causal_mask (d_in[4]) is always 1 in this problem — hardcoded causal.

    char* ws = (char*)d_ws;
    // layout (bytes):
    //   qk [8192][2048] bf16  : 0        .. 33554432   (Q cols 0..1023, K cols 1024..2047)
    //   S  [4][2048][2048]    : 33554432 .. 67108864
    //   vt [1024][8192] bf16  : 67108864 .. 83886080   (V^T, batches side-by-side cols)
    //   xb [8192][1024] bf16  : 83886080 .. 100663296
    //   wT [3][1024][1024]    : 100663296.. 106954752
    unsigned short* qk = (unsigned short*)(ws);
    unsigned short* S = (unsigned short*)(ws + 33554432);
    unsigned short* vt = (unsigned short*)(ws + 67108864);
    unsigned short* xb = (unsigned short*)(ws + 83886080);
    unsigned short* wT = (unsigned short*)(ws + 100663296);

    // A. x->bf16 (8192 blocks) + W->W^T bf16 (3072 blocks), one dispatch
    prep<<<11264, 256, 0, stream>>>(x, Wq, Wk, Wv, xb, wT);
    // B. qk = xb @ [Wq|Wk]   (M=8192, N=2048, K=1024) — 1024 blocks
    gemm_qk<<<dim3(16, 64), 256, 0, stream>>>(xb, wT, qk);
    // C. S = scale * Q K^T — 544 lower-triangle blocks only
    gemm_s<<<544, 256, 0, stream>>>(qk, S);
    // D. softmax (2048 light blocks) + vt GEMM (512 blocks), one dispatch
    sm_vt<<<2560, 256, 0, stream>>>(S, wT + 2 * 1024 * 1024, xb, vt);
    // E. O = P @ V — 512 blocks, complementary kend pairing
    gemm_pv<<<512, 256, 0, stream>>>(S, vt, (float*)d_out);
}

// Round 4
// 238.266 us; speedup vs baseline: 1.3145x; 1.0049x over previous
//
#include <hip/hip_runtime.h>
#include <hip/hip_bf16.h>
#include <stdint.h>

#define BM 128
#define BN 128
#define BK 64

typedef __attribute__((ext_vector_type(8))) short bf16x8;
typedef __attribute__((ext_vector_type(4))) float floatx4;

// ---- helpers ------------------------------------------------------------

__device__ __forceinline__ unsigned short f2bf(float f) {
    unsigned int x;
    __builtin_memcpy(&x, &f, 4);
    unsigned int r = (x + 0x7fffu + ((x >> 16) & 1u)) >> 16;  // RNE
    return (unsigned short)r;
}

__device__ __forceinline__ float bf2f_hi(unsigned int u_hi_masked) {
    float f;
    __builtin_memcpy(&f, &u_hi_masked, 4);
    return f;
}

// async global->LDS, 16B per lane.  LDS dest must be wave-uniform base + lane*16.
// R1 LESSON: the per-lane GLOBAL source order must stay ASCENDING — an XOR
// permutation within the 128B row segment de-coalesced the DMA into 16B
// requests and cost +60% on every staging-bound core (qk 50->80us).
__device__ __forceinline__ void async_copy16(const void* g, void* l) {
    __builtin_amdgcn_global_load_lds(
        (const __attribute__((address_space(1))) void*)(uintptr_t)g,
        (__attribute__((address_space(3))) void*)(uint32_t)(uintptr_t)l,
        16, 0, 0);
}

// ---- prep: fp32->bf16 convert of x  +  W^T bf16 of Wq/Wk/Wv -------------

__global__ __launch_bounds__(256) void prep(const float* __restrict__ x,
                                            const float* __restrict__ Wq,
                                            const float* __restrict__ Wk,
                                            const float* __restrict__ Wv,
                                            unsigned short* __restrict__ xb,
                                            unsigned short* __restrict__ wT) {
    __shared__ float tile[32][33];
    int bid = blockIdx.x;
    int tid = threadIdx.x;
    if (bid < 8192) {  // cvt: 8192 blocks x 256 threads x float4
        int i = bid * 256 + tid;
        float4 v = ((const float4*)x)[i];
        ushort4 o;
        o.x = f2bf(v.x);
        o.y = f2bf(v.y);
        o.z = f2bf(v.z);
        o.w = f2bf(v.w);
        ((ushort4*)xb)[i] = o;
    } else {  // transpose W: 3 x 1024 blocks, 32x32 tiles
        int w = bid - 8192;
        int z = w >> 10;
        int r = w & 1023;
        int bx = (r & 31) * 32;  // input col (n)
        int by = (r >> 5) * 32;  // input row (k)
        const float* W = z == 0 ? Wq : (z == 1 ? Wk : Wv);
        int tx = tid & 31, ty = tid >> 5;  // 32x8
        for (int rr = 0; rr < 32; rr += 8)
            tile[ty + rr][tx] = W[(size_t)(by + ty + rr) * 1024 + bx + tx];
        __syncthreads();
        unsigned short* o = wT + (size_t)z * 1024 * 1024;
        for (int rr = 0; rr < 32; rr += 8)
            o[(size_t)(bx + ty + rr) * 1024 + by + tx] = f2bf(tile[tx][ty + rr]);
    }
}

// ---- padded LDS layout (shared by both cores) ---------------------------
// Segment = 8 tile-rows = one 1KB wave-DMA.  Segment STRIDE 544 shorts
// (512 data + 32 pad = 1088B = 272 dwords == 16 banks mod 32).  A fragment
// ds_read_b128 (16 lanes, fixed kc) spans 2 adjacent segments; the 16-bank
// parity shift + 4-bank kq shift covers all 8 4-bank groups with 8 lanes
// each = conflict-free b128 rate.  Linear layout was 2x (16 lanes on one
// group) — qk's SQ_LDS_BANK_CONFLICT 12.58M = ~49kcyc/CU = ~20.5us/CU of
// serialized LDS time; at 4 blocks/CU the LDS unit is a SHARED saturated
// resource, TLP can't hide it (R3 post-mortem).
// Global per-lane source order stays ascending (R1); only the wave-uniform
// LDS segment base changes (R2 overlap bug fixed by the reserved stride).

#define SEG_STRIDE 544            // shorts: 512 data + 32 pad
#define BUF_SH (16 * SEG_STRIDE)  // 8704 shorts = 17408 B per 128x64 tile

// ---- GEMM core (single-buffer, padded) — qk / s -------------------------
// m97 structure (stage -> sync -> compute -> sync), 4 blocks/CU.
// LDS: 2 x 17408 = 34816B/block; 4 blocks = 139264B <= 160KB.

__device__ __forceinline__ void gemm_core(const unsigned short* __restrict__ A,
                                          int lda,
                                          const unsigned short* __restrict__ B,
                                          int ldb, void* __restrict__ C,
                                          int ldc, bool out_bf16, int kend,
                                          float scale, int m0, int n0) {
    __shared__ __align__(16) unsigned short As[BUF_SH];
    __shared__ __align__(16) unsigned short Bs[BUF_SH];

    int tid = threadIdx.x;
    int lane = tid & 63;
    int wave = tid >> 6;
    int wm = (wave >> 1) * 64;
    int wn = (wave & 1) * 64;
    int fr = lane & 15;  // fragment row (m) / col (n)
    int kq = lane >> 4;  // k-quad

    floatx4 acc[4][4] = {};

    for (int k0 = 0; k0 < kend; k0 += BK) {
#pragma unroll
        for (int q = 0; q < 4; q++) {
            int s = 4 * q + wave;         // 1KB segment, wave-uniform
            int r = s * 8 + (lane >> 3);  // global row (same rows as before)
            int ko = (lane & 7) * 8;      // ascending chunk order!
            int dst = s * SEG_STRIDE + lane * 8;
            async_copy16(A + (size_t)(m0 + r) * lda + k0 + ko, &As[dst]);
            async_copy16(B + (size_t)(n0 + r) * ldb + k0 + ko, &Bs[dst]);
        }
        __syncthreads();  // drains vmcnt before LDS reads

#pragma unroll
        for (int kh = 0; kh < 2; kh++) {
            int kc = kh * 4 + kq;
            bf16x8 af[4], bfg[4];
#pragma unroll
            for (int mi = 0; mi < 4; mi++) {
                int row = wm + mi * 16 + fr;
                af[mi] = *(const bf16x8*)&As[(row >> 3) * SEG_STRIDE +
                                             (row & 7) * 64 + kc * 8];
            }
#pragma unroll
            for (int ni = 0; ni < 4; ni++) {
                int row = wn + ni * 16 + fr;
                bfg[ni] = *(const bf16x8*)&Bs[(row >> 3) * SEG_STRIDE +
                                              (row & 7) * 64 + kc * 8];
            }
#pragma unroll
            for (int mi = 0; mi < 4; mi++)
#pragma unroll
                for (int ni = 0; ni < 4; ni++)
                    acc[mi][ni] = __builtin_amdgcn_mfma_f32_16x16x32_bf16(
                        af[mi], bfg[ni], acc[mi][ni], 0, 0, 0);
        }
        __syncthreads();  // protect LDS before next stage
    }

    // epilogue: C/D layout col=lane&15, row=(lane>>4)*4+reg  (m89/m91-verified)
    int col0 = n0 + wn + fr;
    int rbase = m0 + wm + kq * 4;
    if (out_bf16) {
        unsigned short* Cb = (unsigned short*)C;
#pragma unroll
        for (int mi = 0; mi < 4; mi++)
#pragma unroll
            for (int ni = 0; ni < 4; ni++)
#pragma unroll
                for (int r = 0; r < 4; r++)
                    Cb[(size_t)(rbase + mi * 16 + r) * ldc + col0 + ni * 16] =
                        f2bf(acc[mi][ni][r] * scale);
    } else {
        float* Cb = (float*)C;
#pragma unroll
        for (int mi = 0; mi < 4; mi++)
#pragma unroll
            for (int ni = 0; ni < 4; ni++)
#pragma unroll
                for (int r = 0; r < 4; r++)
                    Cb[(size_t)(rbase + mi * 16 + r) * ldc + col0 + ni * 16] =
                        acc[mi][ni][r] * scale;
    }
}

// ---- GEMM core (double-buffered, padded) — pv / vt ----------------------
// R3-verified.  dbuf (T3-minimum): stage(t+1) issued BEFORE compute(t),
// ONE __syncthreads() (= vmcnt(0)+barrier) per K-step.  For stages running
// 2 blocks/CU (pv: complementary pairing leaves most iters with ONE live
// block; vt: 512 blocks), intra-block prefetch is the only latency hiding.
// LDS: 4 x 17408B = 69632B; 2 blocks/CU.

__device__ __forceinline__ void gemm_core_db(
    const unsigned short* __restrict__ A, int lda,
    const unsigned short* __restrict__ B, int ldb, void* __restrict__ C,
    int ldc, bool out_bf16, int kend, float scale, int m0, int n0) {
    __shared__ __align__(16) unsigned short As[2 * BUF_SH];
    __shared__ __align__(16) unsigned short Bs[2 * BUF_SH];

    int tid = threadIdx.x;
    int lane = tid & 63;
    int wave = tid >> 6;
    int wm = (wave >> 1) * 64;
    int wn = (wave & 1) * 64;
    int fr = lane & 15;  // fragment row (m) / col (n)
    int kq = lane >> 4;  // k-quad

    floatx4 acc[4][4] = {};

    auto stage = [&](int buf, int k0) {
#pragma unroll
        for (int q = 0; q < 4; q++) {
            int s = 4 * q + wave;         // 1KB segment, wave-uniform
            int r = s * 8 + (lane >> 3);  // global row (same rows as sbuf core)
            int ko = (lane & 7) * 8;      // ascending chunk order!
            int dst = buf * BUF_SH + s * SEG_STRIDE + lane * 8;
            async_copy16(A + (size_t)(m0 + r) * lda + k0 + ko, &As[dst]);
            async_copy16(B + (size_t)(n0 + r) * ldb + k0 + ko, &Bs[dst]);
        }
    };

    auto compute = [&](int buf) {
        const unsigned short* as = &As[buf * BUF_SH];
        const unsigned short* bs = &Bs[buf * BUF_SH];
#pragma unroll
        for (int kh = 0; kh < 2; kh++) {
            int kc = kh * 4 + kq;
            bf16x8 af[4], bfg[4];
#pragma unroll
            for (int mi = 0; mi < 4; mi++) {
                int row = wm + mi * 16 + fr;
                af[mi] = *(const bf16x8*)&as[(row >> 3) * SEG_STRIDE +
                                             (row & 7) * 64 + kc * 8];
            }
#pragma unroll
            for (int ni = 0; ni < 4; ni++) {
                int row = wn + ni * 16 + fr;
                bfg[ni] = *(const bf16x8*)&bs[(row >> 3) * SEG_STRIDE +
                                              (row & 7) * 64 + kc * 8];
            }
#pragma unroll
            for (int mi = 0; mi < 4; mi++)
#pragma unroll
                for (int ni = 0; ni < 4; ni++)
                    acc[mi][ni] = __builtin_amdgcn_mfma_f32_16x16x32_bf16(
                        af[mi], bfg[ni], acc[mi][ni], 0, 0, 0);
        }
    };

    // 2-phase: stage(t+1) overlaps compute(t); one barrier per K-step.
    stage(0, 0);
    __syncthreads();
    int nt = kend / BK;
    int cur = 0;
    for (int t = 0; t < nt; t++) {
        if (t + 1 < nt) stage(cur ^ 1, (t + 1) * BK);
        compute(cur);
        __syncthreads();  // drains prefetch + protects buf before rewrite
        cur ^= 1;
    }

    // epilogue: C/D layout col=lane&15, row=(lane>>4)*4+reg
    int col0 = n0 + wn + fr;
    int rbase = m0 + wm + kq * 4;
    if (out_bf16) {
        unsigned short* Cb = (unsigned short*)C;
#pragma unroll
        for (int mi = 0; mi < 4; mi++)
#pragma unroll
            for (int ni = 0; ni < 4; ni++)
#pragma unroll
                for (int r = 0; r < 4; r++)
                    Cb[(size_t)(rbase + mi * 16 + r) * ldc + col0 + ni * 16] =
                        f2bf(acc[mi][ni][r] * scale);
    } else {
        float* Cb = (float*)C;
#pragma unroll
        for (int mi = 0; mi < 4; mi++)
#pragma unroll
            for (int ni = 0; ni < 4; ni++)
#pragma unroll
                for (int r = 0; r < 4; r++)
                    Cb[(size_t)(rbase + mi * 16 + r) * ldc + col0 + ni * 16] =
                        acc[mi][ni][r] * scale;
    }
}

// ---- triangular job decode for the S stage ------------------------------

__device__ __forceinline__ void tri_decode(int r2, int& mb, int& nb) {
    mb = (int)((sqrtf(8.0f * r2 + 1.0f) - 1.0f) * 0.5f);
    while ((mb + 1) * (mb + 2) / 2 <= r2) mb++;
    while (mb * (mb + 1) / 2 > r2) mb--;
    nb = r2 - mb * (mb + 1) / 2;
}

// ---- stage B: qk = xb @ [Wq|Wk]  (M=8192, N=2048, K=1024) ---------------
// 1024 blocks = 4/CU x 16 iters = 64 iters/CU, uniform.

__global__ __launch_bounds__(256, 4) void gemm_qk(
    const unsigned short* __restrict__ xb, const unsigned short* __restrict__ wT,
    unsigned short* __restrict__ qk) {
    gemm_core(xb, 1024, wT, 1024, qk, 2048, true, 1024, 1.0f,
              blockIdx.y * BM, blockIdx.x * BN);
}

// ---- stage C: S = scale * Q K^T, lower-triangle blocks only -------------
// 544 blocks; max CU gets 3 blocks = 48 iters.

__global__ __launch_bounds__(256, 4) void gemm_s(
    const unsigned short* __restrict__ qk, unsigned short* __restrict__ S) {
    int bz = blockIdx.x / 136;
    int mb, nb;
    tri_decode(blockIdx.x - bz * 136, mb, nb);
    const unsigned short* Q = qk + (size_t)bz * 2048 * 2048;
    gemm_core(Q, 2048, Q + 1024, 2048, S + (size_t)bz * 2048 * 2048, 2048,
              true, 1024, 0.03125f, mb * BM, nb * BN);
}

// ---- stage D: softmax (causal, in place)  MERGED WITH  vt = WvT @ xb^T --
// Softmax: ONE row per wave (2048 blocks x 4 waves = 8192 rows exactly).
// R8 bug: a two-rows-per-wave loop here wrote rows 8192..12287 — 16 MB past
// S, straight into vt. Keep the row map 1:1 with the grid.
// R4: vt switched to the R3-verified db core (vt runs 2 blocks/CU — same
// solo-serialization regime where db paid on pv).

__global__ __launch_bounds__(256, 4) void sm_vt(
    unsigned short* __restrict__ S, const unsigned short* __restrict__ wTv,
    const unsigned short* __restrict__ xb, unsigned short* __restrict__ vt) {
    int bid = blockIdx.x;
    if (bid < 512) {  // vt: 8 m-blocks x 64 n-blocks (M=1024 WvT, N=8192 xb)
        gemm_core_db(wTv, 1024, xb, 1024, vt, 8192, true, 1024, 1.0f,
                     (bid >> 6) * BM, (bid & 63) * BN);
        return;
    }
    // softmax: one wave per row, full row in registers (32 f32/lane)
    int lane = threadIdx.x & 63;
    int row = (bid - 512) * 4 + (threadIdx.x >> 6);  // 0..8191
    int i = row & 2047;  // causal row index within batch
    unsigned short* s = S + (size_t)row * 2048;

    uint4 raw[4];
#pragma unroll
    for (int c = 0; c < 4; c++) raw[c] = ((const uint4*)s)[lane + c * 64];

    const float NEG = -1.0e30f;
    float p[32];
    float m = NEG;
#pragma unroll
    for (int c = 0; c < 4; c++) {
        const unsigned int* u = (const unsigned int*)&raw[c];
#pragma unroll
        for (int w = 0; w < 4; w++) {
            int j = c * 512 + lane * 8 + w * 2;
            float f0 = bf2f_hi(u[w] << 16);
            float f1 = bf2f_hi(u[w] & 0xffff0000u);
            f0 = (j <= i) ? f0 : NEG;
            f1 = (j + 1 <= i) ? f1 : NEG;
            p[c * 8 + w * 2] = f0;
            p[c * 8 + w * 2 + 1] = f1;
            m = fmaxf(m, fmaxf(f0, f1));
        }
    }
#pragma unroll
    for (int o = 32; o > 0; o >>= 1) m = fmaxf(m, __shfl_xor(m, o));

    float sum = 0.f;
#pragma unroll
    for (int t = 0; t < 32; t++) {
        p[t] = __expf(p[t] - m);
        sum += p[t];
    }
#pragma unroll
    for (int o = 32; o > 0; o >>= 1) sum += __shfl_xor(sum, o);
    float inv = 1.0f / sum;

#pragma unroll
    for (int c = 0; c < 4; c++) {
        uint4 out;
        unsigned int* u = (unsigned int*)&out;
#pragma unroll
        for (int w = 0; w < 4; w++) {
            unsigned int lo = f2bf(p[c * 8 + w * 2] * inv);
            unsigned int hi = f2bf(p[c * 8 + w * 2 + 1] * inv);
            u[w] = lo | (hi << 16);
        }
        ((uint4*)s)[lane + c * 64] = out;
    }
}

// ---- stage E: O = P @ V, complementary kend pairing ---------------------
// Round-robin block->CU: CU c gets blocks c and c+256. Map b<256 -> j=b
// (mb=j>>5 in 0..7), b>=256 -> j=767-b (mb in 8..15): per-CU iters
// = 2(mb+1) + 2(16-mb) = 34, uniform (vs 64 worst-case with same-mb pairing
// — that mispairing alone made PV 51.7us in R5).
// R3: dbuf core + padded-stride segment layout (see gemm_core_db header).

__global__ __launch_bounds__(256, 4) void gemm_pv(
    const unsigned short* __restrict__ S, const unsigned short* __restrict__ vt,
    float* __restrict__ out) {
    int b = blockIdx.x;
    int j = b < 256 ? b : 767 - b;
    int mb = j >> 5;
    int rem = j & 31;
    int bz = rem >> 3, nb = rem & 7;
    int kend = (mb + 1) * 128;  // P[i][j]==0 for j>i
    gemm_core_db(S + (size_t)bz * 2048 * 2048, 2048, vt + (size_t)bz * 2048,
                 8192, out + (size_t)bz * 2048 * 1024, 1024, false, kend, 1.0f,
                 mb * BM, nb * BN);
}

// ---- launch -------------------------------------------------------------

extern "C" void kernel_launch(void* const* d_in, const int* in_sizes, int n_in,
                              void* d_out, int out_size, void* d_ws,
                              size_t ws_size, hipStream_t stream) {
    const float* x = (const float*)d_in[0];
    const float* Wq = (const float*)d_in[1];
    const float* Wk = (const float*)d_in[2];
    const float* Wv = (const float*)d_in[3];
    // causal_mask (d_in[4]) is always 1 in this problem — hardcoded causal.

    char* ws = (char*)d_ws;
    // layout (bytes):
    //   qk [8192][2048] bf16  : 0        .. 33554432   (Q cols 0..1023, K cols 1024..2047)
    //   S  [4][2048][2048]    : 33554432 .. 67108864
    //   vt [1024][8192] bf16  : 67108864 .. 83886080   (V^T, batches side-by-side cols)
    //   xb [8192][1024] bf16  : 83886080 .. 100663296
    //   wT [3][1024][1024]    : 100663296.. 106954752
    unsigned short* qk = (unsigned short*)(ws);
    unsigned short* S = (unsigned short*)(ws + 33554432);
    unsigned short* vt = (unsigned short*)(ws + 67108864);
    unsigned short* xb = (unsigned short*)(ws + 83886080);
    unsigned short* wT = (unsigned short*)(ws + 100663296);

    // A. x->bf16 (8192 blocks) + W->W^T bf16 (3072 blocks), one dispatch
    prep<<<11264, 256, 0, stream>>>(x, Wq, Wk, Wv, xb, wT);
    // B. qk = xb @ [Wq|Wk]   (M=8192, N=2048, K=1024) — 1024 blocks
    gemm_qk<<<dim3(16, 64), 256, 0, stream>>>(xb, wT, qk);
    // C. S = scale * Q K^T — 544 lower-triangle blocks only
    gemm_s<<<544, 256, 0, stream>>>(qk, S);
    // D. softmax (2048 light blocks) + vt GEMM (512 blocks), one dispatch
    sm_vt<<<2560, 256, 0, stream>>>(S, wT + 2 * 1024 * 1024, xb, vt);
    // E. O = P @ V — 512 blocks, complementary kend pairing
    gemm_pv<<<512, 256, 0, stream>>>(S, vt, (float*)d_out);
}